// Round 4
// baseline (251.199 us; speedup 1.0000x reference)
//
#include <hip/hip_runtime.h>

#define NCH 30
#define CPB 256              // cells per chunk (= THREADS: one cell per thread)
#define THREADS 256
#define F4PA 1920            // float4 per array per chunk = CPB*30/4
#define MAXRES 512           // 2 blocks/CU * 256 CUs (LDS-capped: 2*60KiB < 160KiB)

__device__ __forceinline__ float iou_fn(float x1, float y1, float w1, float h1,
                                        float x2, float y2, float w2, float h2) {
    float a1 = w1 * h1, a2 = w2 * h2;
    float left  = fmaxf(x1 - w1 * 0.5f, x2 - w2 * 0.5f);
    float right = fminf(x1 + w1 * 0.5f, x2 + w2 * 0.5f);
    float top   = fmaxf(y1 - h1 * 0.5f, y2 - h2 * 0.5f);
    float bot   = fminf(y1 + h1 * 0.5f, y2 + h2 * 0.5f);
    float iw = fmaxf(right - left, 0.0f);
    float ih = fmaxf(bot - top, 0.0f);
    float inter = iw * ih;
    float uni = a1 + a2 - inter;
    return (inter > 0.0f) ? (inter / uni) : 0.0f;
}

__device__ __forceinline__ void cell_losses(const float* p, const float* t,
                                            float& coord, float& lobj,
                                            float& lnoobj, float& lclass) {
    float obj_f = (t[0] == 1.0f) ? 1.0f : 0.0f;

    float iou1 = iou_fn(p[1], p[2], p[3], p[4], t[1], t[2], t[3], t[4]);
    float iou2 = iou_fn(t[6], t[7], t[8], t[9], t[1], t[2], t[3], t[4]);
    bool r = iou1 > iou2;

    float px = r ? p[1] : p[6], py = r ? p[2] : p[7];
    float pw = r ? p[3] : p[8], ph = r ? p[4] : p[9];
    float tx = r ? t[1] : t[6], ty = r ? t[2] : t[7];
    float tw = r ? t[3] : t[8], th = r ? t[4] : t[9];

    float dx = px - tx, dy = py - ty;
    float cxy = dx * dx + dy * dy;
    float swv = sqrtf(pw) - sqrtf(tw), shv = sqrtf(ph) - sqrtf(th);
    float cwh = swv * swv + shv * shv;

    float conf_resp  = r ? p[0] : p[5];
    float iou_resp   = r ? iou1 : iou2;
    float conf_other = r ? p[5] : p[0];
    float dconf = conf_resp - iou_resp;

    coord  += obj_f * (cxy + cwh);
    lobj   += obj_f * dconf * dconf;
    lnoobj += obj_f * conf_other * conf_other
            + (1.0f - obj_f) * (p[0] * p[0] + p[5] * p[5]);

    float cls = 0.0f;
#pragma unroll
    for (int i = 10; i < NCH; i++) { float e = p[i] - t[i]; cls += e * e; }
    lclass += obj_f * cls;
}

// Load one chunk (1920 float4 per array) into registers.
// k-th pred load: idx tid + k*256; targ loads rotated by 4 to decorrelate the
// two streams' addresses within the issue window. 8th slot (k==7) covers
// idx 1792..1919 -> only tid<128 participates.
__device__ __forceinline__ void load_chunk(const float4* __restrict__ p4,
                                           const float4* __restrict__ t4,
                                           long long base4, int tid,
                                           float4* rp, float4* rt) {
#pragma unroll
    for (int k = 0; k < 8; k++) {
        const int kt = (k + 4) & 7;
        if (k < 7 || tid < 128)  rp[k]  = p4[base4 + tid + k  * THREADS];
        if (kt < 7 || tid < 128) rt[kt] = t4[base4 + tid + kt * THREADS];
    }
}

__global__ __launch_bounds__(THREADS) void yolo_main(
        const float4* __restrict__ pred4, const float4* __restrict__ targ4,
        float4* __restrict__ partials, int nchunks_full, int n_cells) {
    __shared__ float4 sp4[F4PA];   // 30720 B
    __shared__ float4 st4[F4PA];   // 30720 B

    const int tid = threadIdx.x;
    float coord = 0.f, lobj = 0.f, lnoobj = 0.f, lclass = 0.f;

    float4 rp[8], rt[8];

    int c = blockIdx.x;
    bool have = c < nchunks_full;
    if (have) load_chunk(pred4, targ4, (long long)c * F4PA, tid, rp, rt);

    while (have) {
        int cn = c + gridDim.x;
        bool have_n = cn < nchunks_full;

        __syncthreads();                       // previous compute done with LDS
#pragma unroll
        for (int k = 0; k < 8; k++) {          // drain vmcnt, fill LDS
            if (k < 7 || tid < 128) {
                sp4[tid + k * THREADS] = rp[k];
                st4[tid + k * THREADS] = rt[k];
            }
        }
        __syncthreads();

        if (have_n)                            // prefetch next chunk; loads stay
            load_chunk(pred4, targ4, (long long)cn * F4PA, tid, rp, rt);

        // compute: one cell per thread, all 256 threads
        {
            float p[NCH], t[NCH];
            const float2* pp = reinterpret_cast<const float2*>(sp4) + tid * (NCH / 2);
            const float2* tp = reinterpret_cast<const float2*>(st4) + tid * (NCH / 2);
#pragma unroll
            for (int k = 0; k < NCH / 2; k++) { float2 v = pp[k]; p[2 * k] = v.x; p[2 * k + 1] = v.y; }
#pragma unroll
            for (int k = 0; k < NCH / 2; k++) { float2 v = tp[k]; t[2 * k] = v.x; t[2 * k + 1] = v.y; }
            cell_losses(p, t, coord, lobj, lnoobj, lclass);
        }

        c = cn; have = have_n;
    }

    // tail cells (n_cells % CPB), handled by block 0 with direct loads
    if (blockIdx.x == 0) {
        int cell = nchunks_full * CPB + tid;
        if (cell < n_cells) {
            float p[NCH], t[NCH];
            const float2* pp = reinterpret_cast<const float2*>(pred4) + (long long)cell * (NCH / 2);
            const float2* tp = reinterpret_cast<const float2*>(targ4) + (long long)cell * (NCH / 2);
#pragma unroll
            for (int k = 0; k < NCH / 2; k++) { float2 v = pp[k]; p[2 * k] = v.x; p[2 * k + 1] = v.y; }
#pragma unroll
            for (int k = 0; k < NCH / 2; k++) { float2 v = tp[k]; t[2 * k] = v.x; t[2 * k + 1] = v.y; }
            cell_losses(p, t, coord, lobj, lnoobj, lclass);
        }
    }

    // wave-64 shuffle reduction
#pragma unroll
    for (int off = 32; off > 0; off >>= 1) {
        coord  += __shfl_down(coord, off);
        lobj   += __shfl_down(lobj, off);
        lnoobj += __shfl_down(lnoobj, off);
        lclass += __shfl_down(lclass, off);
    }

    __shared__ float red[4][4];
    int lane = tid & 63;
    int wid  = tid >> 6;
    if (lane == 0) {
        red[wid][0] = coord; red[wid][1] = lobj;
        red[wid][2] = lnoobj; red[wid][3] = lclass;
    }
    __syncthreads();
    if (tid == 0) {
        float s0 = 0.f, s1 = 0.f, s2 = 0.f, s3 = 0.f;
        for (int w = 0; w < 4; w++) {
            s0 += red[w][0]; s1 += red[w][1];
            s2 += red[w][2]; s3 += red[w][3];
        }
        partials[blockIdx.x] = make_float4(s0, s1, s2, s3);
    }
}

__global__ __launch_bounds__(THREADS) void yolo_reduce(
        const float4* __restrict__ partials, int nparts,
        float* __restrict__ out, double inv_bs) {
    double s0 = 0.0, s1 = 0.0, s2 = 0.0, s3 = 0.0;
    for (int i = threadIdx.x; i < nparts; i += THREADS) {
        float4 v = partials[i];
        s0 += (double)v.x; s1 += (double)v.y;
        s2 += (double)v.z; s3 += (double)v.w;
    }
#pragma unroll
    for (int off = 32; off > 0; off >>= 1) {
        s0 += __shfl_down(s0, off);
        s1 += __shfl_down(s1, off);
        s2 += __shfl_down(s2, off);
        s3 += __shfl_down(s3, off);
    }
    __shared__ double red[4][4];
    int lane = threadIdx.x & 63;
    int wid  = threadIdx.x >> 6;
    if (lane == 0) {
        red[wid][0] = s0; red[wid][1] = s1;
        red[wid][2] = s2; red[wid][3] = s3;
    }
    __syncthreads();
    if (threadIdx.x == 0) {
        double a0 = 0, a1 = 0, a2 = 0, a3 = 0;
        for (int w = 0; w < 4; w++) {
            a0 += red[w][0]; a1 += red[w][1];
            a2 += red[w][2]; a3 += red[w][3];
        }
        double cd = a0 * 5.0 * inv_bs;   // LAMBDA_COORD
        double o  = a1 * inv_bs;
        double n  = a2 * 0.5 * inv_bs;   // LAMBDA_NOOBJ
        double cl = a3 * inv_bs;
        out[0] = (float)cd;
        out[1] = (float)o;
        out[2] = (float)n;
        out[3] = (float)cl;
        out[4] = (float)(cd + o + n + cl);
    }
}

extern "C" void kernel_launch(void* const* d_in, const int* in_sizes, int n_in,
                              void* d_out, int out_size, void* d_ws, size_t ws_size,
                              hipStream_t stream) {
    const float4* pred4 = (const float4*)d_in[0];
    const float4* targ4 = (const float4*)d_in[1];
    float* out = (float*)d_out;
    float4* partials = (float4*)d_ws;

    int n_cells = in_sizes[0] / NCH;          // batch * 7 * 7
    int batch   = n_cells / 49;
    int nchunks_full = n_cells / CPB;

    // balanced grid: all blocks do exactly `iters` chunks, all fully resident
    int grid;
    if (nchunks_full <= 0) {
        grid = 1;
    } else {
        int iters = (nchunks_full + MAXRES - 1) / MAXRES;
        grid = (nchunks_full + iters - 1) / iters;
    }

    yolo_main<<<grid, THREADS, 0, stream>>>(pred4, targ4, partials, nchunks_full, n_cells);
    yolo_reduce<<<1, THREADS, 0, stream>>>(partials, grid, out, 1.0 / (double)batch);
}

// Round 5
// 206.407 us; speedup vs baseline: 1.2170x; 1.2170x over previous
//
#include <hip/hip_runtime.h>

#define NCH 30
#define CPB 256              // cells per chunk (= THREADS: one cell per thread)
#define THREADS 256
#define CHUNK_F (CPB * NCH)  // 7680 floats per array per chunk (30720 B)
#define SLOT_F 256           // floats per DMA slot: 64 lanes x 4 floats = 1024 B
#define NSLOTA 30            // slots per array per chunk
#define GRID 256             // 1 block/CU (LDS 120 KiB caps residency at 1)

__device__ __forceinline__ void dma16(const float* g, const float* l) {
    // wave-collective: each lane supplies g (base + lane*16); dest is
    // wave-uniform LDS base, HW scatters lane i to l + i*16
    __builtin_amdgcn_global_load_lds(
        (const __attribute__((address_space(1))) void*)g,
        (__attribute__((address_space(3))) void*)l,
        16, 0, 0);
}

__device__ __forceinline__ float iou_fn(float x1, float y1, float w1, float h1,
                                        float x2, float y2, float w2, float h2) {
    float a1 = w1 * h1, a2 = w2 * h2;
    float left  = fmaxf(x1 - w1 * 0.5f, x2 - w2 * 0.5f);
    float right = fminf(x1 + w1 * 0.5f, x2 + w2 * 0.5f);
    float top   = fmaxf(y1 - h1 * 0.5f, y2 - h2 * 0.5f);
    float bot   = fminf(y1 + h1 * 0.5f, y2 + h2 * 0.5f);
    float iw = fmaxf(right - left, 0.0f);
    float ih = fmaxf(bot - top, 0.0f);
    float inter = iw * ih;
    float uni = a1 + a2 - inter;
    return (inter > 0.0f) ? (inter / uni) : 0.0f;
}

__device__ __forceinline__ void cell_losses(const float* p, const float* t,
                                            float& coord, float& lobj,
                                            float& lnoobj, float& lclass) {
    float obj_f = (t[0] == 1.0f) ? 1.0f : 0.0f;

    float iou1 = iou_fn(p[1], p[2], p[3], p[4], t[1], t[2], t[3], t[4]);
    float iou2 = iou_fn(t[6], t[7], t[8], t[9], t[1], t[2], t[3], t[4]);
    bool r = iou1 > iou2;

    float px = r ? p[1] : p[6], py = r ? p[2] : p[7];
    float pw = r ? p[3] : p[8], ph = r ? p[4] : p[9];
    float tx = r ? t[1] : t[6], ty = r ? t[2] : t[7];
    float tw = r ? t[3] : t[8], th = r ? t[4] : t[9];

    float dx = px - tx, dy = py - ty;
    float cxy = dx * dx + dy * dy;
    float swv = sqrtf(pw) - sqrtf(tw), shv = sqrtf(ph) - sqrtf(th);
    float cwh = swv * swv + shv * shv;

    float conf_resp  = r ? p[0] : p[5];
    float iou_resp   = r ? iou1 : iou2;
    float conf_other = r ? p[5] : p[0];
    float dconf = conf_resp - iou_resp;

    coord  += obj_f * (cxy + cwh);
    lobj   += obj_f * dconf * dconf;
    lnoobj += obj_f * conf_other * conf_other
            + (1.0f - obj_f) * (p[0] * p[0] + p[5] * p[5]);

    float cls = 0.0f;
#pragma unroll
    for (int i = 10; i < NCH; i++) { float e = p[i] - t[i]; cls += e * e; }
    lclass += obj_f * cls;
}

__device__ __forceinline__ void issue_chunk_dma(const float* __restrict__ pred,
                                                const float* __restrict__ targ,
                                                long long base, int wid, int lane4,
                                                float* sp, float* st) {
    // 60 wave-level DMAs per chunk (30 per array), round-robined over 4 waves
    for (int s = wid; s < 2 * NSLOTA; s += 4) {
        const float* g;
        const float* l;
        if (s < NSLOTA) { g = pred + base + s * SLOT_F + lane4;            l = sp + s * SLOT_F; }
        else            { g = targ + base + (s - NSLOTA) * SLOT_F + lane4; l = st + (s - NSLOTA) * SLOT_F; }
        dma16(g, l);
    }
}

__global__ __launch_bounds__(THREADS) void yolo_main(
        const float* __restrict__ pred, const float* __restrict__ targ,
        float4* __restrict__ partials, int nchunks, int n_cells) {
    __shared__ float sb[2][2][CHUNK_F];   // [buffer][pred/targ][7680] = 120 KiB

    const int tid = threadIdx.x;
    const int wid = tid >> 6;
    const int lane4 = (tid & 63) * 4;

    float coord = 0.f, lobj = 0.f, lnoobj = 0.f, lclass = 0.f;

    int c = blockIdx.x;
    int buf = 0;
    if (c < nchunks)
        issue_chunk_dma(pred, targ, (long long)c * CHUNK_F, wid, lane4,
                        &sb[0][0][0], &sb[0][1][0]);

    while (c < nchunks) {
        int cn = c + gridDim.x;

        // completes chunk c's DMA (vmcnt drain at barrier) and fences the
        // other buffer (compute of chunk c-1 finished before this barrier)
        __syncthreads();

        if (cn < nchunks) {
            int ob = buf ^ 1;
            issue_chunk_dma(pred, targ, (long long)cn * CHUNK_F, wid, lane4,
                            &sb[ob][0][0], &sb[ob][1][0]);
        }

        // compute: one cell per thread from LDS
        {
            float p[NCH], t[NCH];
            const float2* pp = reinterpret_cast<const float2*>(&sb[buf][0][0]) + tid * (NCH / 2);
            const float2* tp = reinterpret_cast<const float2*>(&sb[buf][1][0]) + tid * (NCH / 2);
#pragma unroll
            for (int k = 0; k < NCH / 2; k++) { float2 v = pp[k]; p[2 * k] = v.x; p[2 * k + 1] = v.y; }
#pragma unroll
            for (int k = 0; k < NCH / 2; k++) { float2 v = tp[k]; t[2 * k] = v.x; t[2 * k + 1] = v.y; }
            cell_losses(p, t, coord, lobj, lnoobj, lclass);
        }

        c = cn;
        buf ^= 1;
    }

    // tail cells (n_cells % CPB — zero for this shape), block 0, direct loads
    if (blockIdx.x == 0) {
        int cell = nchunks * CPB + tid;
        if (cell < n_cells) {
            float p[NCH], t[NCH];
            const float2* pp = reinterpret_cast<const float2*>(pred) + (long long)cell * (NCH / 2);
            const float2* tp = reinterpret_cast<const float2*>(targ) + (long long)cell * (NCH / 2);
#pragma unroll
            for (int k = 0; k < NCH / 2; k++) { float2 v = pp[k]; p[2 * k] = v.x; p[2 * k + 1] = v.y; }
#pragma unroll
            for (int k = 0; k < NCH / 2; k++) { float2 v = tp[k]; t[2 * k] = v.x; t[2 * k + 1] = v.y; }
            cell_losses(p, t, coord, lobj, lnoobj, lclass);
        }
    }

    // wave-64 shuffle reduction
#pragma unroll
    for (int off = 32; off > 0; off >>= 1) {
        coord  += __shfl_down(coord, off);
        lobj   += __shfl_down(lobj, off);
        lnoobj += __shfl_down(lnoobj, off);
        lclass += __shfl_down(lclass, off);
    }

    __shared__ float red[4][4];
    int lane = tid & 63;
    if (lane == 0) {
        red[wid][0] = coord; red[wid][1] = lobj;
        red[wid][2] = lnoobj; red[wid][3] = lclass;
    }
    __syncthreads();
    if (tid == 0) {
        float s0 = 0.f, s1 = 0.f, s2 = 0.f, s3 = 0.f;
        for (int w = 0; w < 4; w++) {
            s0 += red[w][0]; s1 += red[w][1];
            s2 += red[w][2]; s3 += red[w][3];
        }
        partials[blockIdx.x] = make_float4(s0, s1, s2, s3);
    }
}

__global__ __launch_bounds__(THREADS) void yolo_reduce(
        const float4* __restrict__ partials, int nparts,
        float* __restrict__ out, double inv_bs) {
    double s0 = 0.0, s1 = 0.0, s2 = 0.0, s3 = 0.0;
    for (int i = threadIdx.x; i < nparts; i += THREADS) {
        float4 v = partials[i];
        s0 += (double)v.x; s1 += (double)v.y;
        s2 += (double)v.z; s3 += (double)v.w;
    }
#pragma unroll
    for (int off = 32; off > 0; off >>= 1) {
        s0 += __shfl_down(s0, off);
        s1 += __shfl_down(s1, off);
        s2 += __shfl_down(s2, off);
        s3 += __shfl_down(s3, off);
    }
    __shared__ double red[4][4];
    int lane = threadIdx.x & 63;
    int wid  = threadIdx.x >> 6;
    if (lane == 0) {
        red[wid][0] = s0; red[wid][1] = s1;
        red[wid][2] = s2; red[wid][3] = s3;
    }
    __syncthreads();
    if (threadIdx.x == 0) {
        double a0 = 0, a1 = 0, a2 = 0, a3 = 0;
        for (int w = 0; w < 4; w++) {
            a0 += red[w][0]; a1 += red[w][1];
            a2 += red[w][2]; a3 += red[w][3];
        }
        double cd = a0 * 5.0 * inv_bs;   // LAMBDA_COORD
        double o  = a1 * inv_bs;
        double n  = a2 * 0.5 * inv_bs;   // LAMBDA_NOOBJ
        double cl = a3 * inv_bs;
        out[0] = (float)cd;
        out[1] = (float)o;
        out[2] = (float)n;
        out[3] = (float)cl;
        out[4] = (float)(cd + o + n + cl);
    }
}

extern "C" void kernel_launch(void* const* d_in, const int* in_sizes, int n_in,
                              void* d_out, int out_size, void* d_ws, size_t ws_size,
                              hipStream_t stream) {
    const float* pred = (const float*)d_in[0];
    const float* targ = (const float*)d_in[1];
    float* out = (float*)d_out;
    float4* partials = (float4*)d_ws;

    int n_cells = in_sizes[0] / NCH;          // batch * 7 * 7
    int batch   = n_cells / 49;
    int nchunks = n_cells / CPB;

    int grid = nchunks < GRID ? nchunks : GRID;
    if (grid < 1) grid = 1;                   // block 0 still handles the tail

    yolo_main<<<grid, THREADS, 0, stream>>>(pred, targ, partials, nchunks, n_cells);
    yolo_reduce<<<1, THREADS, 0, stream>>>(partials, grid, out, 1.0 / (double)batch);
}

// Round 7
// 191.114 us; speedup vs baseline: 1.3144x; 1.0800x over previous
//
#include <hip/hip_runtime.h>

#define NCH 30
#define CPB 128              // cells per chunk
#define THREADS 256
#define MAXRES 1280          // 5 blocks/CU * 256 CUs (LDS: 31 KiB/block)

typedef float fvec4 __attribute__((ext_vector_type(4)));

__device__ __forceinline__ float iou_fn(float x1, float y1, float w1, float h1,
                                        float x2, float y2, float w2, float h2) {
    float a1 = w1 * h1, a2 = w2 * h2;
    float left  = fmaxf(x1 - w1 * 0.5f, x2 - w2 * 0.5f);
    float right = fminf(x1 + w1 * 0.5f, x2 + w2 * 0.5f);
    float top   = fmaxf(y1 - h1 * 0.5f, y2 - h2 * 0.5f);
    float bot   = fminf(y1 + h1 * 0.5f, y2 + h2 * 0.5f);
    float iw = fmaxf(right - left, 0.0f);
    float ih = fmaxf(bot - top, 0.0f);
    float inter = iw * ih;
    float uni = a1 + a2 - inter;
    return (inter > 0.0f) ? (inter / uni) : 0.0f;
}

__device__ __forceinline__ void cell_losses(const float* p, const float* t,
                                            float& coord, float& lobj,
                                            float& lnoobj, float& lclass) {
    float obj_f = (t[0] == 1.0f) ? 1.0f : 0.0f;

    float iou1 = iou_fn(p[1], p[2], p[3], p[4], t[1], t[2], t[3], t[4]);
    float iou2 = iou_fn(t[6], t[7], t[8], t[9], t[1], t[2], t[3], t[4]);
    bool r = iou1 > iou2;

    float px = r ? p[1] : p[6], py = r ? p[2] : p[7];
    float pw = r ? p[3] : p[8], ph = r ? p[4] : p[9];
    float tx = r ? t[1] : t[6], ty = r ? t[2] : t[7];
    float tw = r ? t[3] : t[8], th = r ? t[4] : t[9];

    float dx = px - tx, dy = py - ty;
    float cxy = dx * dx + dy * dy;
    float swv = sqrtf(pw) - sqrtf(tw), shv = sqrtf(ph) - sqrtf(th);
    float cwh = swv * swv + shv * shv;

    float conf_resp  = r ? p[0] : p[5];
    float iou_resp   = r ? iou1 : iou2;
    float conf_other = r ? p[5] : p[0];
    float dconf = conf_resp - iou_resp;

    coord  += obj_f * (cxy + cwh);
    lobj   += obj_f * dconf * dconf;
    lnoobj += obj_f * conf_other * conf_other
            + (1.0f - obj_f) * (p[0] * p[0] + p[5] * p[5]);

    float cls = 0.0f;
#pragma unroll
    for (int i = 10; i < NCH; i++) { float e = p[i] - t[i]; cls += e * e; }
    lclass += obj_f * cls;
}

__global__ __launch_bounds__(THREADS) void yolo_main(
        const float* __restrict__ pred, const float* __restrict__ targ,
        float4* __restrict__ partials, int n_cells) {
    __shared__ float sp[CPB * NCH];   // 15360 B
    __shared__ float st[CPB * NCH];   // 15360 B

    const int tid = threadIdx.x;
    const int nchunks = (n_cells + CPB - 1) / CPB;
    const long long total_floats = (long long)n_cells * NCH;

    float coord = 0.f, lobj = 0.f, lnoobj = 0.f, lclass = 0.f;

    for (int c = blockIdx.x; c < nchunks; c += gridDim.x) {
        const long long base = (long long)c * (CPB * NCH);
        const long long rem = total_floats - base;
        const int nflt = rem < (long long)(CPB * NCH) ? (int)rem : (CPB * NCH);
        const int n4 = nflt >> 2;

        const fvec4* p4 = reinterpret_cast<const fvec4*>(pred + base);
        const fvec4* t4 = reinterpret_cast<const fvec4*>(targ + base);
        fvec4* sp4 = reinterpret_cast<fvec4*>(sp);
        fvec4* st4 = reinterpret_cast<fvec4*>(st);
        for (int i = tid; i < n4; i += THREADS) {
            // nontemporal: read-once stream — no-allocate / streaming cache policy
            fvec4 a = __builtin_nontemporal_load(p4 + i);
            fvec4 b = __builtin_nontemporal_load(t4 + i);
            sp4[i] = a;
            st4[i] = b;
        }
        for (int i = (n4 << 2) + tid; i < nflt; i += THREADS) {   // scalar tail
            sp[i] = pred[base + i];
            st[i] = targ[base + i];
        }
        __syncthreads();

        if (tid < CPB) {
            long long cell = (long long)c * CPB + tid;
            if (cell < n_cells) {
                const float* p = sp + tid * NCH;
                const float* t = st + tid * NCH;
                cell_losses(p, t, coord, lobj, lnoobj, lclass);
            }
        }
        __syncthreads();
    }

    // wave-64 shuffle reduction
#pragma unroll
    for (int off = 32; off > 0; off >>= 1) {
        coord  += __shfl_down(coord, off);
        lobj   += __shfl_down(lobj, off);
        lnoobj += __shfl_down(lnoobj, off);
        lclass += __shfl_down(lclass, off);
    }

    __shared__ float red[4][4];
    int lane = tid & 63;
    int wid  = tid >> 6;
    if (lane == 0) {
        red[wid][0] = coord; red[wid][1] = lobj;
        red[wid][2] = lnoobj; red[wid][3] = lclass;
    }
    __syncthreads();
    if (tid == 0) {
        float s0 = 0.f, s1 = 0.f, s2 = 0.f, s3 = 0.f;
        for (int w = 0; w < 4; w++) {
            s0 += red[w][0]; s1 += red[w][1];
            s2 += red[w][2]; s3 += red[w][3];
        }
        partials[blockIdx.x] = make_float4(s0, s1, s2, s3);
    }
}

__global__ __launch_bounds__(THREADS) void yolo_reduce(
        const float4* __restrict__ partials, int nparts,
        float* __restrict__ out, double inv_bs) {
    double s0 = 0.0, s1 = 0.0, s2 = 0.0, s3 = 0.0;
    for (int i = threadIdx.x; i < nparts; i += THREADS) {
        float4 v = partials[i];
        s0 += (double)v.x; s1 += (double)v.y;
        s2 += (double)v.z; s3 += (double)v.w;
    }
#pragma unroll
    for (int off = 32; off > 0; off >>= 1) {
        s0 += __shfl_down(s0, off);
        s1 += __shfl_down(s1, off);
        s2 += __shfl_down(s2, off);
        s3 += __shfl_down(s3, off);
    }
    __shared__ double red[4][4];
    int lane = threadIdx.x & 63;
    int wid  = threadIdx.x >> 6;
    if (lane == 0) {
        red[wid][0] = s0; red[wid][1] = s1;
        red[wid][2] = s2; red[wid][3] = s3;
    }
    __syncthreads();
    if (threadIdx.x == 0) {
        double a0 = 0, a1 = 0, a2 = 0, a3 = 0;
        for (int w = 0; w < 4; w++) {
            a0 += red[w][0]; a1 += red[w][1];
            a2 += red[w][2]; a3 += red[w][3];
        }
        double cd = a0 * 5.0 * inv_bs;   // LAMBDA_COORD
        double o  = a1 * inv_bs;
        double n  = a2 * 0.5 * inv_bs;   // LAMBDA_NOOBJ
        double cl = a3 * inv_bs;
        out[0] = (float)cd;
        out[1] = (float)o;
        out[2] = (float)n;
        out[3] = (float)cl;
        out[4] = (float)(cd + o + n + cl);
    }
}

extern "C" void kernel_launch(void* const* d_in, const int* in_sizes, int n_in,
                              void* d_out, int out_size, void* d_ws, size_t ws_size,
                              hipStream_t stream) {
    const float* pred = (const float*)d_in[0];
    const float* targ = (const float*)d_in[1];
    float* out = (float*)d_out;
    float4* partials = (float4*)d_ws;

    int n_cells = in_sizes[0] / NCH;          // batch * 7 * 7
    int batch   = n_cells / 49;
    int nchunks = (n_cells + CPB - 1) / CPB;

    // balanced grid: every block runs the same number of chunk iterations
    int grid;
    if (nchunks <= 0) {
        grid = 1;
    } else {
        int iters = (nchunks + MAXRES - 1) / MAXRES;
        grid = (nchunks + iters - 1) / iters;
    }

    yolo_main<<<grid, THREADS, 0, stream>>>(pred, targ, partials, n_cells);
    yolo_reduce<<<1, THREADS, 0, stream>>>(partials, grid, out, 1.0 / (double)batch);
}

// Round 8
// 189.743 us; speedup vs baseline: 1.3239x; 1.0072x over previous
//
#include <hip/hip_runtime.h>

#define NCH 30
#define F2PC 15              // float2 per cell
#define CPB 256              // cells per chunk (= THREADS: one cell per thread)
#define THREADS 256
#define MAXRES 512           // 2 blocks/CU * 256 CUs (LDS-capped: 2*60KiB < 160KiB)

typedef float fvec2 __attribute__((ext_vector_type(2)));

__device__ __forceinline__ float iou_fn(float x1, float y1, float w1, float h1,
                                        float x2, float y2, float w2, float h2) {
    float a1 = w1 * h1, a2 = w2 * h2;
    float left  = fmaxf(x1 - w1 * 0.5f, x2 - w2 * 0.5f);
    float right = fminf(x1 + w1 * 0.5f, x2 + w2 * 0.5f);
    float top   = fmaxf(y1 - h1 * 0.5f, y2 - h2 * 0.5f);
    float bot   = fminf(y1 + h1 * 0.5f, y2 + h2 * 0.5f);
    float iw = fmaxf(right - left, 0.0f);
    float ih = fmaxf(bot - top, 0.0f);
    float inter = iw * ih;
    float uni = a1 + a2 - inter;
    return (inter > 0.0f) ? (inter / uni) : 0.0f;
}

__device__ __forceinline__ void cell_losses(const float* p, const float* t,
                                            float& coord, float& lobj,
                                            float& lnoobj, float& lclass) {
    float obj_f = (t[0] == 1.0f) ? 1.0f : 0.0f;

    float iou1 = iou_fn(p[1], p[2], p[3], p[4], t[1], t[2], t[3], t[4]);
    float iou2 = iou_fn(t[6], t[7], t[8], t[9], t[1], t[2], t[3], t[4]);
    bool r = iou1 > iou2;

    float px = r ? p[1] : p[6], py = r ? p[2] : p[7];
    float pw = r ? p[3] : p[8], ph = r ? p[4] : p[9];
    float tx = r ? t[1] : t[6], ty = r ? t[2] : t[7];
    float tw = r ? t[3] : t[8], th = r ? t[4] : t[9];

    float dx = px - tx, dy = py - ty;
    float cxy = dx * dx + dy * dy;
    float swv = sqrtf(pw) - sqrtf(tw), shv = sqrtf(ph) - sqrtf(th);
    float cwh = swv * swv + shv * shv;

    float conf_resp  = r ? p[0] : p[5];
    float iou_resp   = r ? iou1 : iou2;
    float conf_other = r ? p[5] : p[0];
    float dconf = conf_resp - iou_resp;

    coord  += obj_f * (cxy + cwh);
    lobj   += obj_f * dconf * dconf;
    lnoobj += obj_f * conf_other * conf_other
            + (1.0f - obj_f) * (p[0] * p[0] + p[5] * p[5]);

    float cls = 0.0f;
#pragma unroll
    for (int i = 10; i < NCH; i++) { float e = p[i] - t[i]; cls += e * e; }
    lclass += obj_f * cls;
}

__global__ __launch_bounds__(THREADS) void yolo_main(
        const fvec2* __restrict__ pred2, const fvec2* __restrict__ targ2,
        float4* __restrict__ partials, int nchunks_full, int n_cells) {
    __shared__ fvec2 sp[CPB * F2PC];   // 30720 B
    __shared__ fvec2 st[CPB * F2PC];   // 30720 B

    const int tid = threadIdx.x;
    float coord = 0.f, lobj = 0.f, lnoobj = 0.f, lclass = 0.f;

    fvec2 rp[F2PC], rt[F2PC];

    int c = blockIdx.x;
    bool have = c < nchunks_full;
    if (have) {
        const long long b = (long long)c * (CPB * F2PC);
#pragma unroll
        for (int k = 0; k < F2PC; k++) {
            rp[k] = __builtin_nontemporal_load(pred2 + b + tid + k * THREADS);
            rt[k] = __builtin_nontemporal_load(targ2 + b + tid + k * THREADS);
        }
    }

    while (have) {
        int cn = c + gridDim.x;
        bool have_n = cn < nchunks_full;

        __syncthreads();                       // previous compute done with LDS
#pragma unroll
        for (int k = 0; k < F2PC; k++) {       // drain vmcnt, fill LDS
            sp[tid + k * THREADS] = rp[k];
            st[tid + k * THREADS] = rt[k];
        }
        __syncthreads();

        if (have_n) {                          // prefetch next chunk; loads stay
            const long long b = (long long)cn * (CPB * F2PC);   // in flight across compute
#pragma unroll
            for (int k = 0; k < F2PC; k++) {
                rp[k] = __builtin_nontemporal_load(pred2 + b + tid + k * THREADS);
                rt[k] = __builtin_nontemporal_load(targ2 + b + tid + k * THREADS);
            }
        }

        // compute: one cell per thread, all 256 threads
        {
            float p[NCH], t[NCH];
            const fvec2* pp = sp + tid * F2PC;
            const fvec2* tp = st + tid * F2PC;
#pragma unroll
            for (int k = 0; k < F2PC; k++) { fvec2 v = pp[k]; p[2 * k] = v.x; p[2 * k + 1] = v.y; }
#pragma unroll
            for (int k = 0; k < F2PC; k++) { fvec2 v = tp[k]; t[2 * k] = v.x; t[2 * k + 1] = v.y; }
            cell_losses(p, t, coord, lobj, lnoobj, lclass);
        }

        c = cn; have = have_n;
    }

    // tail cells (n_cells % CPB — zero for this shape), block 0, direct loads
    if (blockIdx.x == 0) {
        int cell = nchunks_full * CPB + tid;
        if (cell < n_cells) {
            float p[NCH], t[NCH];
            const fvec2* pp = pred2 + (long long)cell * F2PC;
            const fvec2* tp = targ2 + (long long)cell * F2PC;
#pragma unroll
            for (int k = 0; k < F2PC; k++) { fvec2 v = pp[k]; p[2 * k] = v.x; p[2 * k + 1] = v.y; }
#pragma unroll
            for (int k = 0; k < F2PC; k++) { fvec2 v = tp[k]; t[2 * k] = v.x; t[2 * k + 1] = v.y; }
            cell_losses(p, t, coord, lobj, lnoobj, lclass);
        }
    }

    // wave-64 shuffle reduction
#pragma unroll
    for (int off = 32; off > 0; off >>= 1) {
        coord  += __shfl_down(coord, off);
        lobj   += __shfl_down(lobj, off);
        lnoobj += __shfl_down(lnoobj, off);
        lclass += __shfl_down(lclass, off);
    }

    __shared__ float red[4][4];
    int lane = tid & 63;
    int wid  = tid >> 6;
    if (lane == 0) {
        red[wid][0] = coord; red[wid][1] = lobj;
        red[wid][2] = lnoobj; red[wid][3] = lclass;
    }
    __syncthreads();
    if (tid == 0) {
        float s0 = 0.f, s1 = 0.f, s2 = 0.f, s3 = 0.f;
        for (int w = 0; w < 4; w++) {
            s0 += red[w][0]; s1 += red[w][1];
            s2 += red[w][2]; s3 += red[w][3];
        }
        partials[blockIdx.x] = make_float4(s0, s1, s2, s3);
    }
}

__global__ __launch_bounds__(THREADS) void yolo_reduce(
        const float4* __restrict__ partials, int nparts,
        float* __restrict__ out, double inv_bs) {
    double s0 = 0.0, s1 = 0.0, s2 = 0.0, s3 = 0.0;
    for (int i = threadIdx.x; i < nparts; i += THREADS) {
        float4 v = partials[i];
        s0 += (double)v.x; s1 += (double)v.y;
        s2 += (double)v.z; s3 += (double)v.w;
    }
#pragma unroll
    for (int off = 32; off > 0; off >>= 1) {
        s0 += __shfl_down(s0, off);
        s1 += __shfl_down(s1, off);
        s2 += __shfl_down(s2, off);
        s3 += __shfl_down(s3, off);
    }
    __shared__ double red[4][4];
    int lane = threadIdx.x & 63;
    int wid  = threadIdx.x >> 6;
    if (lane == 0) {
        red[wid][0] = s0; red[wid][1] = s1;
        red[wid][2] = s2; red[wid][3] = s3;
    }
    __syncthreads();
    if (threadIdx.x == 0) {
        double a0 = 0, a1 = 0, a2 = 0, a3 = 0;
        for (int w = 0; w < 4; w++) {
            a0 += red[w][0]; a1 += red[w][1];
            a2 += red[w][2]; a3 += red[w][3];
        }
        double cd = a0 * 5.0 * inv_bs;   // LAMBDA_COORD
        double o  = a1 * inv_bs;
        double n  = a2 * 0.5 * inv_bs;   // LAMBDA_NOOBJ
        double cl = a3 * inv_bs;
        out[0] = (float)cd;
        out[1] = (float)o;
        out[2] = (float)n;
        out[3] = (float)cl;
        out[4] = (float)(cd + o + n + cl);
    }
}

extern "C" void kernel_launch(void* const* d_in, const int* in_sizes, int n_in,
                              void* d_out, int out_size, void* d_ws, size_t ws_size,
                              hipStream_t stream) {
    const fvec2* pred2 = (const fvec2*)d_in[0];
    const fvec2* targ2 = (const fvec2*)d_in[1];
    float* out = (float*)d_out;
    float4* partials = (float4*)d_ws;

    int n_cells = in_sizes[0] / NCH;          // batch * 7 * 7
    int batch   = n_cells / 49;
    int nchunks_full = n_cells / CPB;

    // balanced grid: every block runs the same number of chunk iterations
    int grid;
    if (nchunks_full <= 0) {
        grid = 1;
    } else {
        int iters = (nchunks_full + MAXRES - 1) / MAXRES;
        grid = (nchunks_full + iters - 1) / iters;
    }

    yolo_main<<<grid, THREADS, 0, stream>>>(pred2, targ2, partials, nchunks_full, n_cells);
    yolo_reduce<<<1, THREADS, 0, stream>>>(partials, grid, out, 1.0 / (double)batch);
}